// Round 6
// baseline (1645.296 us; speedup 1.0000x reference)
//
#include <hip/hip_runtime.h>
#include <math.h>

#define DIM 1024
#define P0 512
#define H 16
#define HD 64
#define B 2
#define S 1024
#define PT 1536   // P0 + S

typedef __attribute__((ext_vector_type(8))) short short8v;    // bf16 MFMA frag
typedef __attribute__((ext_vector_type(4))) float f32x4;
typedef __attribute__((ext_vector_type(8))) unsigned short ushort8v;
typedef __attribute__((ext_vector_type(4))) unsigned short ushort4v;

__device__ __forceinline__ unsigned short bf16_rne(float x) {
  unsigned u = __builtin_bit_cast(unsigned, x);
  u += 0x7FFFu + ((u >> 16) & 1u);
  return (unsigned short)(u >> 16);
}
__device__ __forceinline__ float bf16_f(unsigned short h) {
  unsigned u = ((unsigned)h) << 16;
  return __builtin_bit_cast(float, u);
}

// ---------------------------------------------------------------- mag ----
__global__ __launch_bounds__(256) void k_mag(const float* __restrict__ zr,
                                             const float* __restrict__ zi,
                                             float* __restrict__ mag, int n4) {
  int i = blockIdx.x * blockDim.x + threadIdx.x;
  if (i < n4) {
    float4 a = ((const float4*)zr)[i];
    float4 b = ((const float4*)zi)[i];
    float4 o;
    o.x = sqrtf(a.x * a.x + b.x * b.x);
    o.y = sqrtf(a.y * a.y + b.y * b.y);
    o.z = sqrtf(a.z * a.z + b.z * b.z);
    o.w = sqrtf(a.w * a.w + b.w * b.w);
    ((float4*)mag)[i] = o;
  }
}

// ------------------------------------------------------------- pattern ----
__global__ __launch_bounds__(256) void k_patt(const float* __restrict__ stored,
                                              const float* __restrict__ mag,
                                              float* __restrict__ patt, int n4) {
  int i = blockIdx.x * blockDim.x + threadIdx.x;
  if (i < n4) {
    int d4 = i & (DIM / 4 - 1);
    int p  = (i >> 8) % PT;
    int b  = i / (PT * (DIM / 4));
    float4 v;
    if (p < P0) {
      v = ((const float4*)stored)[(size_t)p * (DIM / 4) + d4];
    } else {
      v = ((const float4*)mag)[((size_t)(b * S + (p - P0))) * (DIM / 4) + d4];
    }
    ((float4*)patt)[i] = v;
  }
}

// ---------------------------------------------- plain hi/lo bf16 split ----
__global__ __launch_bounds__(256) void k_split_plain(const float* __restrict__ X,
                                                     unsigned short* __restrict__ hi,
                                                     unsigned short* __restrict__ lo,
                                                     int n4) {
  int i = blockIdx.x * 256 + threadIdx.x;
  if (i >= n4) return;
  float4 v = ((const float4*)X)[(size_t)i];
  float xs[4] = {v.x, v.y, v.z, v.w};
  ushort4v hv, lv;
#pragma unroll
  for (int j = 0; j < 4; ++j) {
    unsigned short hb = bf16_rne(xs[j]);
    hv[j] = hb;
    lv[j] = bf16_rne(xs[j] - bf16_f(hb));
  }
  ((ushort4v*)hi)[(size_t)i] = hv;
  ((ushort4v*)lo)[(size_t)i] = lv;
}

// ------------------------------------------------------- MFMA GEMM --------
// C(M,N) = A @ W^T with A,W pre-split hi/lo bf16 row-major (K-contig).
// 128x128 tile, BK=32, 256 threads = 4 waves (2x2), 3-product split.
// Epilogue modes: 0 = fp32 C + bias; 1 = head-major hi/lo bf16
// ([b*16+h][p][d], rpb rows per batch); 2 = V^T hi/lo ([b*16+h][d][p]).
// aremap: A row r -> r + 512 + 512*b (reads mag rows out of patt).
__global__ __launch_bounds__(256, 2) void k_gemm_mfma(
    const unsigned short* __restrict__ Ah, const unsigned short* __restrict__ Al,
    const unsigned short* __restrict__ Wh, const unsigned short* __restrict__ Wl,
    const float* __restrict__ bias, float* __restrict__ Cf,
    unsigned short* __restrict__ Ohi, unsigned short* __restrict__ Olo,
    int M, int N, int K, int mode, int rpb, int aremap) {
  __shared__ short8v lds[4][4 * 132];   // Ah, Al, Wh, Wl frag-major tiles
  const int t = threadIdx.x;
  const int w = t >> 6, lane = t & 63;
  const int l16 = lane & 15, l4 = lane >> 4;
  const int wr = w >> 1, wc = w & 1;
  const int bm = blockIdx.y, bn = blockIdx.x;

  f32x4 acc[4][4];
#pragma unroll
  for (int mi = 0; mi < 4; ++mi)
#pragma unroll
    for (int nj = 0; nj < 4; ++nj) acc[mi][nj] = (f32x4){0.f, 0.f, 0.f, 0.f};

  for (int k0 = 0; k0 < K; k0 += 32) {
    __syncthreads();
#pragma unroll
    for (int rep = 0; rep < 2; ++rep) {
      int u = rep * 256 + t;
      int kb = u & 3, r = u >> 2;
      int agr = bm * 128 + r;
      int ar = aremap ? (agr + 512 + ((agr >> 10) << 9)) : agr;
      size_t ga = (size_t)ar * K + k0 + kb * 8;
      size_t gw = (size_t)(bn * 128 + r) * K + k0 + kb * 8;
      int li = kb * 132 + r;
      lds[0][li] = *(const short8v*)(Ah + ga);
      lds[1][li] = *(const short8v*)(Al + ga);
      lds[2][li] = *(const short8v*)(Wh + gw);
      lds[3][li] = *(const short8v*)(Wl + gw);
    }
    __syncthreads();
    short8v af[4][2], bf[4][2];
#pragma unroll
    for (int mi = 0; mi < 4; ++mi) {
      int li = l4 * 132 + wr * 64 + mi * 16 + l16;
      af[mi][0] = lds[0][li];
      af[mi][1] = lds[1][li];
    }
#pragma unroll
    for (int nj = 0; nj < 4; ++nj) {
      int li = l4 * 132 + wc * 64 + nj * 16 + l16;
      bf[nj][0] = lds[2][li];
      bf[nj][1] = lds[3][li];
    }
#pragma unroll
    for (int mi = 0; mi < 4; ++mi)
#pragma unroll
      for (int nj = 0; nj < 4; ++nj) {
        acc[mi][nj] = __builtin_amdgcn_mfma_f32_16x16x32_bf16(af[mi][0], bf[nj][0], acc[mi][nj], 0, 0, 0);
        acc[mi][nj] = __builtin_amdgcn_mfma_f32_16x16x32_bf16(af[mi][0], bf[nj][1], acc[mi][nj], 0, 0, 0);
        acc[mi][nj] = __builtin_amdgcn_mfma_f32_16x16x32_bf16(af[mi][1], bf[nj][0], acc[mi][nj], 0, 0, 0);
      }
  }

#pragma unroll
  for (int mi = 0; mi < 4; ++mi)
#pragma unroll
    for (int nj = 0; nj < 4; ++nj)
#pragma unroll
      for (int i = 0; i < 4; ++i) {
        int rg = bm * 128 + wr * 64 + mi * 16 + l4 * 4 + i;
        int c  = bn * 128 + wc * 64 + nj * 16 + l16;
        float v = acc[mi][nj][i];
        if (mode == 0) {
          Cf[(size_t)rg * N + c] = v + (bias ? bias[c] : 0.f);
        } else {
          int b = rg >= rpb ? 1 : 0;
          int p = rg - b * rpb;
          int hh = c >> 6, d = c & 63;
          size_t o = (mode == 1)
                         ? ((((size_t)(b * 16 + hh)) * rpb + p) * 64 + d)
                         : ((((size_t)(b * 16 + hh)) * 64 + d) * (size_t)rpb + p);
          unsigned short hb = bf16_rne(v);
          Ohi[o] = hb;
          Olo[o] = bf16_rne(v - bf16_f(hb));
        }
      }
}

// ------------------------------------------------- MFMA attention step ----
// Block = 16 query rows of one (b,h), 512 threads = 8 waves. Wave w owns
// p-slice [w*192,(w+1)*192). Scores in registers; sparsemax via cross-wave
// reductions (parity-buffered LDS); PV weights stream through per-wave LDS.
// LDS ~35 KB + 64-VGPR cap -> 4 blocks/CU (32 waves). XCD-swizzled grid.
#define WSTR 40  // ushort stride of wbuf rows

__global__ __launch_bounds__(512, 8) void k_attn_mfma(
    const unsigned short* __restrict__ shi, const unsigned short* __restrict__ slo,
    const unsigned short* __restrict__ khi, const unsigned short* __restrict__ klo,
    const unsigned short* __restrict__ vthi, const unsigned short* __restrict__ vtlo,
    const float* __restrict__ log_temp,
    unsigned short* __restrict__ swhi, unsigned short* __restrict__ swlo,
    unsigned short* __restrict__ ohi, unsigned short* __restrict__ olo) {
  __shared__ float part[8][2][2][20];             // 5120 B reduction scratch
  __shared__ unsigned short wbufh[8][16 * WSTR];  // 10240 B per-wave weights hi
  __shared__ unsigned short wbufl[8][16 * WSTR];  // 10240 B per-wave weights lo
  __shared__ float red2[8][16][20];               // 10240 B dt-chunked reduce
  const int t = threadIdx.x;
  const int w = t >> 6, lane = t & 63;
  const int l16 = lane & 15, l4 = lane >> 4;
  // XCD-aware swizzle: grid 2048 = 8 XCDs x 256; keep each (b,h)'s 64
  // tiles on one XCD so its L2 holds that K/V panel (T1, bijective).
  const int bid = blockIdx.x;
  const int tile = (bid & 7) * 256 + (bid >> 3);
  const int stile = tile & 63;
  const int bh = tile >> 6;
  const int h = bh & 15;
  const int s0 = stile * 16;

  float lt = log_temp[h];
  lt = fminf(fmaxf(lt, -4.f), 4.f);
  const float inv_scale = 1.f / (8.f * expf(lt));

  const size_t arow = ((size_t)bh * S + s0 + l16) * HD + 8 * l4;
  short8v ahi0 = *(const short8v*)(shi + arow);
  short8v ahi1 = *(const short8v*)(shi + arow + 32);
  short8v alo0 = *(const short8v*)(slo + arow);
  short8v alo1 = *(const short8v*)(slo + arow + 32);

  float z0[6][4], z1[6][4];
  const size_t kb = (size_t)bh * PT * HD;
#pragma unroll
  for (int pp = 0; pp < 6; ++pp) {
    const int pt0 = w * 12 + pp * 2;
    const size_t k0 = kb + ((size_t)(pt0 * 16 + l16)) * HD + 8 * l4;
    const size_t k1 = k0 + 16 * HD;
    f32x4 a0 = {0.f, 0.f, 0.f, 0.f}, a1 = {0.f, 0.f, 0.f, 0.f};
    {
      short8v b00 = *(const short8v*)(khi + k0);
      short8v b01 = *(const short8v*)(khi + k0 + 32);
      short8v b10 = *(const short8v*)(khi + k1);
      short8v b11 = *(const short8v*)(khi + k1 + 32);
      a0 = __builtin_amdgcn_mfma_f32_16x16x32_bf16(ahi0, b00, a0, 0, 0, 0);
      a1 = __builtin_amdgcn_mfma_f32_16x16x32_bf16(ahi0, b10, a1, 0, 0, 0);
      a0 = __builtin_amdgcn_mfma_f32_16x16x32_bf16(ahi1, b01, a0, 0, 0, 0);
      a1 = __builtin_amdgcn_mfma_f32_16x16x32_bf16(ahi1, b11, a1, 0, 0, 0);
      a0 = __builtin_amdgcn_mfma_f32_16x16x32_bf16(alo0, b00, a0, 0, 0, 0);
      a1 = __builtin_amdgcn_mfma_f32_16x16x32_bf16(alo0, b10, a1, 0, 0, 0);
      a0 = __builtin_amdgcn_mfma_f32_16x16x32_bf16(alo1, b01, a0, 0, 0, 0);
      a1 = __builtin_amdgcn_mfma_f32_16x16x32_bf16(alo1, b11, a1, 0, 0, 0);
    }
    {
      short8v c00 = *(const short8v*)(klo + k0);
      short8v c01 = *(const short8v*)(klo + k0 + 32);
      short8v c10 = *(const short8v*)(klo + k1);
      short8v c11 = *(const short8v*)(klo + k1 + 32);
      a0 = __builtin_amdgcn_mfma_f32_16x16x32_bf16(ahi0, c00, a0, 0, 0, 0);
      a1 = __builtin_amdgcn_mfma_f32_16x16x32_bf16(ahi0, c10, a1, 0, 0, 0);
      a0 = __builtin_amdgcn_mfma_f32_16x16x32_bf16(ahi1, c01, a0, 0, 0, 0);
      a1 = __builtin_amdgcn_mfma_f32_16x16x32_bf16(ahi1, c11, a1, 0, 0, 0);
    }
#pragma unroll
    for (int i = 0; i < 4; ++i) {
      const int sg = s0 + l4 * 4 + i;
      const int p0i = pt0 * 16 + l16;
      z0[pp][i] = (p0i > P0 + sg) ? -1e9f : a0[i] * inv_scale;
      z1[pp][i] = (p0i + 16 > P0 + sg) ? -1e9f : a1[i] * inv_scale;
    }
  }

  // ---- row max ----
  float mx[4];
#pragma unroll
  for (int i = 0; i < 4; ++i) {
    float m = -1e30f;
#pragma unroll
    for (int pp = 0; pp < 6; ++pp) m = fmaxf(m, fmaxf(z0[pp][i], z1[pp][i]));
    mx[i] = m;
  }
#pragma unroll
  for (int off = 1; off <= 8; off <<= 1)
#pragma unroll
    for (int i = 0; i < 4; ++i) mx[i] = fmaxf(mx[i], __shfl_xor(mx[i], off, 64));
  if (l16 == 0) {
#pragma unroll
    for (int i = 0; i < 4; ++i) part[w][0][0][l4 * 4 + i] = mx[i];
  }
  __syncthreads();
  float tlo[4], thi[4];
  {
    float m4[4] = {-1e30f, -1e30f, -1e30f, -1e30f};
#pragma unroll
    for (int ww = 0; ww < 8; ++ww) {
      f32x4 pv = *(const f32x4*)&part[ww][0][0][l4 * 4];
#pragma unroll
      for (int i = 0; i < 4; ++i) m4[i] = fmaxf(m4[i], pv[i]);
    }
#pragma unroll
    for (int i = 0; i < 4; ++i) { thi[i] = m4[i]; tlo[i] = m4[i] - 1.f; }
  }

  // ---- bisection ----
  for (int it = 0; it < 10; ++it) {
    const int sl = (it + 1) & 1;
    float s4[4];
#pragma unroll
    for (int i = 0; i < 4; ++i) {
      const float mid = 0.5f * (tlo[i] + thi[i]);
      float s = 0.f;
#pragma unroll
      for (int pp = 0; pp < 6; ++pp)
        s += fmaxf(z0[pp][i] - mid, 0.f) + fmaxf(z1[pp][i] - mid, 0.f);
      s4[i] = s;
    }
#pragma unroll
    for (int off = 1; off <= 8; off <<= 1)
#pragma unroll
      for (int i = 0; i < 4; ++i) s4[i] += __shfl_xor(s4[i], off, 64);
    if (l16 == 0) {
#pragma unroll
      for (int i = 0; i < 4; ++i) part[w][sl][0][l4 * 4 + i] = s4[i];
    }
    __syncthreads();
    float rs[4] = {0.f, 0.f, 0.f, 0.f};
#pragma unroll
    for (int ww = 0; ww < 8; ++ww) {
      f32x4 pv = *(const f32x4*)&part[ww][sl][0][l4 * 4];
#pragma unroll
      for (int i = 0; i < 4; ++i) rs[i] += pv[i];
    }
#pragma unroll
    for (int i = 0; i < 4; ++i) {
      const float mid = 0.5f * (tlo[i] + thi[i]);
      if (rs[i] >= 1.f) tlo[i] = mid; else thi[i] = mid;
    }
  }

  // ---- Michelot exact finalize ----
  float tau[4];
#pragma unroll
  for (int i = 0; i < 4; ++i) tau[i] = tlo[i];
  for (int it = 0; it < 4; ++it) {
    const int sl = (11 + it) & 1;
    float c4[4], s4[4];
#pragma unroll
    for (int i = 0; i < 4; ++i) {
      float c = 0.f, s = 0.f;
#pragma unroll
      for (int pp = 0; pp < 6; ++pp) {
        float a = z0[pp][i];
        if (a > tau[i]) { c += 1.f; s += a; }
        float b = z1[pp][i];
        if (b > tau[i]) { c += 1.f; s += b; }
      }
      c4[i] = c; s4[i] = s;
    }
#pragma unroll
    for (int off = 1; off <= 8; off <<= 1)
#pragma unroll
      for (int i = 0; i < 4; ++i) {
        c4[i] += __shfl_xor(c4[i], off, 64);
        s4[i] += __shfl_xor(s4[i], off, 64);
      }
    if (l16 == 0) {
#pragma unroll
      for (int i = 0; i < 4; ++i) {
        part[w][sl][0][l4 * 4 + i] = c4[i];
        part[w][sl][1][l4 * 4 + i] = s4[i];
      }
    }
    __syncthreads();
    float rc[4] = {0.f, 0.f, 0.f, 0.f}, rs[4] = {0.f, 0.f, 0.f, 0.f};
#pragma unroll
    for (int ww = 0; ww < 8; ++ww) {
      f32x4 pc = *(const f32x4*)&part[ww][sl][0][l4 * 4];
      f32x4 ps = *(const f32x4*)&part[ww][sl][1][l4 * 4];
#pragma unroll
      for (int i = 0; i < 4; ++i) { rc[i] += pc[i]; rs[i] += ps[i]; }
    }
#pragma unroll
    for (int i = 0; i < 4; ++i) tau[i] = (rs[i] - 1.f) / rc[i];
  }

  // ---- PV ----
  f32x4 acc[4];
#pragma unroll
  for (int dt = 0; dt < 4; ++dt) acc[dt] = (f32x4){0.f, 0.f, 0.f, 0.f};
  const size_t vb = (size_t)bh * HD * PT;
  unsigned short* wh = wbufh[w];
  unsigned short* wl = wbufl[w];
#pragma unroll
  for (int kk = 0; kk < 6; ++kk) {
    const int ks = w * 6 + kk;
#pragma unroll
    for (int i = 0; i < 4; ++i) {
      const int row = l4 * 4 + i;
      float w0 = fmaxf(z0[kk][i] - tau[i], 0.f);
      float w1 = fmaxf(z1[kk][i] - tau[i], 0.f);
      unsigned short h0 = bf16_rne(w0);
      unsigned short h1 = bf16_rne(w1);
      wh[row * WSTR + l16] = h0;
      wl[row * WSTR + l16] = bf16_rne(w0 - bf16_f(h0));
      wh[row * WSTR + 16 + l16] = h1;
      wl[row * WSTR + 16 + l16] = bf16_rne(w1 - bf16_f(h1));
    }
    asm volatile("s_waitcnt lgkmcnt(0)" ::: "memory");  // wave-local W->R
    __builtin_amdgcn_sched_barrier(0);
    short8v wah = *(const short8v*)(wh + l16 * WSTR + 8 * l4);
    short8v wal = *(const short8v*)(wl + l16 * WSTR + 8 * l4);
#pragma unroll
    for (int dt = 0; dt < 4; ++dt) {
      const size_t vo = vb + (size_t)(dt * 16 + l16) * PT + ks * 32 + 8 * l4;
      short8v vh = *(const short8v*)(vthi + vo);
      short8v vl = *(const short8v*)(vtlo + vo);
      acc[dt] = __builtin_amdgcn_mfma_f32_16x16x32_bf16(wah, vh, acc[dt], 0, 0, 0);
      acc[dt] = __builtin_amdgcn_mfma_f32_16x16x32_bf16(wah, vl, acc[dt], 0, 0, 0);
      acc[dt] = __builtin_amdgcn_mfma_f32_16x16x32_bf16(wal, vh, acc[dt], 0, 0, 0);
    }
  }

  // ---- cross-wave reduce, dt-chunked (LDS-lean) + writes ----
  for (int dt = 0; dt < 4; ++dt) {
    __syncthreads();   // red2 free (prev chunk consumed / wbuf reads done)
#pragma unroll
    for (int i = 0; i < 4; ++i)
      red2[w][l4 * 4 + i][l16] = acc[dt][i];
    __syncthreads();
    if (t < 256) {
      const int row = t >> 4, d16 = t & 15;
      float sum = 0.f;
#pragma unroll
      for (int ww = 0; ww < 8; ++ww) sum += red2[ww][row][d16];
      const int d = dt * 16 + d16;
      const int sg = s0 + row;
      unsigned short hb = bf16_rne(sum);
      unsigned short lb = bf16_rne(sum - bf16_f(hb));
      const size_t rw = ((size_t)((bh >> 4) * S + sg)) * DIM + h * HD + d;
      swhi[rw] = hb;
      swlo[rw] = lb;
      const size_t oi = ((size_t)bh * S + sg) * HD + d;
      ohi[oi] = hb;
      olo[oi] = lb;
    }
  }
}

// ----------------------------------------------------------- layernorm ----
__global__ __launch_bounds__(256) void k_layernorm(float* __restrict__ out,
                                                   const float* __restrict__ gamma,
                                                   const float* __restrict__ beta) {
  const int W = 2 * DIM;
  const int r = blockIdx.x;
  float* row = out + (size_t)r * W;
  const int t = threadIdx.x;
  float4 vals[2];
  float sum = 0.f, sq = 0.f;
#pragma unroll
  for (int i = 0; i < 2; ++i) {
    float4 v = *(const float4*)(row + (i * 256 + t) * 4);
    vals[i] = v;
    sum += v.x + v.y + v.z + v.w;
    sq += v.x * v.x + v.y * v.y + v.z * v.z + v.w * v.w;
  }
#pragma unroll
  for (int off = 32; off >= 1; off >>= 1) {
    sum += __shfl_xor(sum, off, 64);
    sq  += __shfl_xor(sq,  off, 64);
  }
  __shared__ float rs[4], rq[4];
  const int wave = t >> 6, lane = t & 63;
  if (lane == 0) { rs[wave] = sum; rq[wave] = sq; }
  __syncthreads();
  sum = rs[0] + rs[1] + rs[2] + rs[3];
  sq  = rq[0] + rq[1] + rq[2] + rq[3];
  const float mean = sum / W;
  const float var = sq / W - mean * mean;
  const float rstd = rsqrtf(var + 1e-5f);
#pragma unroll
  for (int i = 0; i < 2; ++i) {
    int base = (i * 256 + t) * 4;
    float4 v = vals[i];
    float4 g = *(const float4*)(gamma + base);
    float4 bb = *(const float4*)(beta + base);
    v.x = (v.x - mean) * rstd * g.x + bb.x;
    v.y = (v.y - mean) * rstd * g.y + bb.y;
    v.z = (v.z - mean) * rstd * g.z + bb.z;
    v.w = (v.w - mean) * rstd * g.w + bb.w;
    *(float4*)(row + base) = v;
  }
}

// ---------------------------------------------------------------- launch --
extern "C" void kernel_launch(void* const* d_in, const int* in_sizes, int n_in,
                              void* d_out, int out_size, void* d_ws, size_t ws_size,
                              hipStream_t stream) {
  const float* zr       = (const float*)d_in[0];
  const float* zi       = (const float*)d_in[1];
  const float* stored   = (const float*)d_in[3];
  const float* Wq       = (const float*)d_in[4];
  const float* Wk       = (const float*)d_in[5];
  const float* Wv       = (const float*)d_in[6];
  const float* Wo       = (const float*)d_in[7];
  const float* bo       = (const float*)d_in[8];
  const float* log_temp = (const float*)d_in[9];
  const float* gamma    = (const float*)d_in[10];
  const float* beta     = (const float*)d_in[11];
  float* out = (float*)d_out;

  // --- workspace layout, 64 MB peak with lifetime overlays ---
  char* base = (char*)d_ws;
  float* patt = (float*)(base + (size_t)0);                       // 0-12 MB
  unsigned short* vthi = (unsigned short*)(base + (size_t)0);     // 0-6  (over dead patt)
  unsigned short* vtlo = (unsigned short*)(base + (6u << 20));    // 6-12
  unsigned short* phi  = (unsigned short*)(base + (12u << 20));   // 12-18
  unsigned short* plo  = (unsigned short*)(base + (18u << 20));   // 18-24
  unsigned short* swhi = (unsigned short*)(base + (12u << 20));   // 12-16 (over dead phi/plo)
  unsigned short* swlo = (unsigned short*)(base + (16u << 20));   // 16-20
  unsigned short* wqh  = (unsigned short*)(base + (24u << 20));   // 24-26
  unsigned short* wql  = (unsigned short*)(base + (26u << 20));   // 26-28
  unsigned short* wkh  = (unsigned short*)(base + (28u << 20));   // 28-30
  unsigned short* wkl  = (unsigned short*)(base + (30u << 20));   // 30-32
  unsigned short* wvh  = (unsigned short*)(base + (32u << 20));   // 32-34
  unsigned short* wvl  = (unsigned short*)(base + (34u << 20));   // 34-36
  unsigned short* woh  = (unsigned short*)(base + (24u << 20));   // 24-28 (over dead wq/wk)
  unsigned short* wol  = (unsigned short*)(base + (28u << 20));   // 28-32
  float* mag = (float*)(base + (36u << 20));                      // 36-44
  unsigned short* qhi = (unsigned short*)(base + (36u << 20));    // 36-40 (over dead mag)
  unsigned short* qlo = (unsigned short*)(base + (40u << 20));    // 40-44
  unsigned short* s1hi = (unsigned short*)(base + (44u << 20));   // 44-48
  unsigned short* s1lo = (unsigned short*)(base + (48u << 20));   // 48-52
  unsigned short* khi  = (unsigned short*)(base + (52u << 20));   // 52-58
  unsigned short* klo  = (unsigned short*)(base + (58u << 20));   // 58-64

  const int n4 = B * S * DIM / 4;            // 524288
  k_mag<<<(n4 + 255) / 256, 256, 0, stream>>>(zr, zi, mag, n4);
  const int p4 = B * PT * DIM / 4;           // 786432
  k_patt<<<(p4 + 255) / 256, 256, 0, stream>>>(stored, mag, patt, p4);

  // splits: patterns + projection weights
  k_split_plain<<<p4 / 256, 256, 0, stream>>>(patt, phi, plo, p4);
  const int w4 = DIM * DIM / 4;              // 262144
  k_split_plain<<<w4 / 256, 256, 0, stream>>>(Wq, wqh, wql, w4);
  k_split_plain<<<w4 / 256, 256, 0, stream>>>(Wk, wkh, wkl, w4);
  k_split_plain<<<w4 / 256, 256, 0, stream>>>(Wv, wvh, wvl, w4);

  // Q = mag @ Wq^T  (A rows remapped into patt), head-major hi/lo out
  dim3 gq(1024 / 128, 2048 / 128);
  k_gemm_mfma<<<gq, 256, 0, stream>>>(phi, plo, wqh, wql, nullptr, nullptr,
                                      qhi, qlo, 2048, 1024, 1024, 1, 1024, 1);
  // K = patt @ Wk^T, head-major hi/lo out
  dim3 gkv(1024 / 128, 3072 / 128);
  k_gemm_mfma<<<gkv, 256, 0, stream>>>(phi, plo, wkh, wkl, nullptr, nullptr,
                                       khi, klo, 3072, 1024, 1024, 1, 1536, 0);
  // V = patt @ Wv^T, V^T hi/lo out
  k_gemm_mfma<<<gkv, 256, 0, stream>>>(phi, plo, wvh, wvl, nullptr, nullptr,
                                       vthi, vtlo, 3072, 1024, 1024, 2, 1536, 0);

  // Wo split (after wq/wk dead)
  const int wo4 = 2 * DIM * DIM / 4;         // 524288
  k_split_plain<<<wo4 / 256, 256, 0, stream>>>(Wo, woh, wol, wo4);

  const int ablocks = B * H * (S / 16);      // 2048
  k_attn_mfma<<<ablocks, 512, 0, stream>>>(qhi, qlo, khi, klo, vthi, vtlo,
                                           log_temp, swhi, swlo, s1hi, s1lo);
  k_attn_mfma<<<ablocks, 512, 0, stream>>>(s1hi, s1lo, khi, klo, vthi, vtlo,
                                           log_temp, swhi, swlo, qhi, qlo);
  k_attn_mfma<<<ablocks, 512, 0, stream>>>(qhi, qlo, khi, klo, vthi, vtlo,
                                           log_temp, swhi, swlo, s1hi, s1lo);

  // out = sw @ Wo^T + bo, fp32
  dim3 go(2048 / 128, 2048 / 128);
  k_gemm_mfma<<<go, 256, 0, stream>>>(swhi, swlo, woh, wol, bo, out,
                                      nullptr, nullptr, 2048, 2048, 1024, 0, 0, 0);
  k_layernorm<<<B * S, 256, 0, stream>>>(out, gamma, beta);
}

// Round 7
// 882.550 us; speedup vs baseline: 1.8643x; 1.8643x over previous
//
#include <hip/hip_runtime.h>
#include <math.h>

#define DIM 1024
#define P0 512
#define H 16
#define HD 64
#define B 2
#define S 1024
#define PT 1536   // P0 + S

typedef __attribute__((ext_vector_type(8))) short short8v;    // bf16 MFMA frag
typedef __attribute__((ext_vector_type(4))) float f32x4;
typedef __attribute__((ext_vector_type(8))) unsigned short ushort8v;
typedef __attribute__((ext_vector_type(4))) unsigned short ushort4v;

__device__ __forceinline__ unsigned short bf16_rne(float x) {
  unsigned u = __builtin_bit_cast(unsigned, x);
  u += 0x7FFFu + ((u >> 16) & 1u);
  return (unsigned short)(u >> 16);
}
__device__ __forceinline__ float bf16_f(unsigned short h) {
  unsigned u = ((unsigned)h) << 16;
  return __builtin_bit_cast(float, u);
}

// ---------------------------------------------------------------- mag ----
__global__ __launch_bounds__(256) void k_mag(const float* __restrict__ zr,
                                             const float* __restrict__ zi,
                                             float* __restrict__ mag, int n4) {
  int i = blockIdx.x * blockDim.x + threadIdx.x;
  if (i < n4) {
    float4 a = ((const float4*)zr)[i];
    float4 b = ((const float4*)zi)[i];
    float4 o;
    o.x = sqrtf(a.x * a.x + b.x * b.x);
    o.y = sqrtf(a.y * a.y + b.y * b.y);
    o.z = sqrtf(a.z * a.z + b.z * b.z);
    o.w = sqrtf(a.w * a.w + b.w * b.w);
    ((float4*)mag)[i] = o;
  }
}

// ------------------------------------------------------------- pattern ----
__global__ __launch_bounds__(256) void k_patt(const float* __restrict__ stored,
                                              const float* __restrict__ mag,
                                              float* __restrict__ patt, int n4) {
  int i = blockIdx.x * blockDim.x + threadIdx.x;
  if (i < n4) {
    int d4 = i & (DIM / 4 - 1);
    int p  = (i >> 8) % PT;
    int b  = i / (PT * (DIM / 4));
    float4 v;
    if (p < P0) {
      v = ((const float4*)stored)[(size_t)p * (DIM / 4) + d4];
    } else {
      v = ((const float4*)mag)[((size_t)(b * S + (p - P0))) * (DIM / 4) + d4];
    }
    ((float4*)patt)[i] = v;
  }
}

// ---------------------------------------------- plain hi/lo bf16 split ----
__global__ __launch_bounds__(256) void k_split_plain(const float* __restrict__ X,
                                                     unsigned short* __restrict__ hi,
                                                     unsigned short* __restrict__ lo,
                                                     int n4) {
  int i = blockIdx.x * 256 + threadIdx.x;
  if (i >= n4) return;
  float4 v = ((const float4*)X)[(size_t)i];
  float xs[4] = {v.x, v.y, v.z, v.w};
  ushort4v hv, lv;
#pragma unroll
  for (int j = 0; j < 4; ++j) {
    unsigned short hb = bf16_rne(xs[j]);
    hv[j] = hb;
    lv[j] = bf16_rne(xs[j] - bf16_f(hb));
  }
  ((ushort4v*)hi)[(size_t)i] = hv;
  ((ushort4v*)lo)[(size_t)i] = lv;
}

// ------------------------------------------------------- MFMA GEMM --------
// C(M,N) = A @ W^T with A,W pre-split hi/lo bf16 row-major (K-contig).
// 128x128 tile, BK=32, 256 threads = 4 waves (2x2), 3-product split.
// Epilogue modes: 0 = fp32 C + bias; 1 = head-major hi/lo bf16
// ([b*16+h][p][d], rpb rows per batch); 2 = V^T hi/lo ([b*16+h][d][p]).
// aremap: A row r -> r + 512 + 512*b (reads mag rows out of patt).
__global__ __launch_bounds__(256, 2) void k_gemm_mfma(
    const unsigned short* __restrict__ Ah, const unsigned short* __restrict__ Al,
    const unsigned short* __restrict__ Wh, const unsigned short* __restrict__ Wl,
    const float* __restrict__ bias, float* __restrict__ Cf,
    unsigned short* __restrict__ Ohi, unsigned short* __restrict__ Olo,
    int M, int N, int K, int mode, int rpb, int aremap) {
  __shared__ short8v lds[4][4 * 132];   // Ah, Al, Wh, Wl frag-major tiles
  const int t = threadIdx.x;
  const int w = t >> 6, lane = t & 63;
  const int l16 = lane & 15, l4 = lane >> 4;
  const int wr = w >> 1, wc = w & 1;
  const int bm = blockIdx.y, bn = blockIdx.x;

  f32x4 acc[4][4];
#pragma unroll
  for (int mi = 0; mi < 4; ++mi)
#pragma unroll
    for (int nj = 0; nj < 4; ++nj) acc[mi][nj] = (f32x4){0.f, 0.f, 0.f, 0.f};

  for (int k0 = 0; k0 < K; k0 += 32) {
    __syncthreads();
#pragma unroll
    for (int rep = 0; rep < 2; ++rep) {
      int u = rep * 256 + t;
      int kb = u & 3, r = u >> 2;
      int agr = bm * 128 + r;
      int ar = aremap ? (agr + 512 + ((agr >> 10) << 9)) : agr;
      size_t ga = (size_t)ar * K + k0 + kb * 8;
      size_t gw = (size_t)(bn * 128 + r) * K + k0 + kb * 8;
      int li = kb * 132 + r;
      lds[0][li] = *(const short8v*)(Ah + ga);
      lds[1][li] = *(const short8v*)(Al + ga);
      lds[2][li] = *(const short8v*)(Wh + gw);
      lds[3][li] = *(const short8v*)(Wl + gw);
    }
    __syncthreads();
    short8v af[4][2], bf[4][2];
#pragma unroll
    for (int mi = 0; mi < 4; ++mi) {
      int li = l4 * 132 + wr * 64 + mi * 16 + l16;
      af[mi][0] = lds[0][li];
      af[mi][1] = lds[1][li];
    }
#pragma unroll
    for (int nj = 0; nj < 4; ++nj) {
      int li = l4 * 132 + wc * 64 + nj * 16 + l16;
      bf[nj][0] = lds[2][li];
      bf[nj][1] = lds[3][li];
    }
#pragma unroll
    for (int mi = 0; mi < 4; ++mi)
#pragma unroll
      for (int nj = 0; nj < 4; ++nj) {
        acc[mi][nj] = __builtin_amdgcn_mfma_f32_16x16x32_bf16(af[mi][0], bf[nj][0], acc[mi][nj], 0, 0, 0);
        acc[mi][nj] = __builtin_amdgcn_mfma_f32_16x16x32_bf16(af[mi][0], bf[nj][1], acc[mi][nj], 0, 0, 0);
        acc[mi][nj] = __builtin_amdgcn_mfma_f32_16x16x32_bf16(af[mi][1], bf[nj][0], acc[mi][nj], 0, 0, 0);
      }
  }

#pragma unroll
  for (int mi = 0; mi < 4; ++mi)
#pragma unroll
    for (int nj = 0; nj < 4; ++nj)
#pragma unroll
      for (int i = 0; i < 4; ++i) {
        int rg = bm * 128 + wr * 64 + mi * 16 + l4 * 4 + i;
        int c  = bn * 128 + wc * 64 + nj * 16 + l16;
        float v = acc[mi][nj][i];
        if (mode == 0) {
          Cf[(size_t)rg * N + c] = v + (bias ? bias[c] : 0.f);
        } else {
          int b = rg >= rpb ? 1 : 0;
          int p = rg - b * rpb;
          int hh = c >> 6, d = c & 63;
          size_t o = (mode == 1)
                         ? ((((size_t)(b * 16 + hh)) * rpb + p) * 64 + d)
                         : ((((size_t)(b * 16 + hh)) * 64 + d) * (size_t)rpb + p);
          unsigned short hb = bf16_rne(v);
          Ohi[o] = hb;
          Olo[o] = bf16_rne(v - bf16_f(hb));
        }
      }
}

// ------------------------------------------------- MFMA attention step ----
// Block = 16 query rows of one (b,h), 512 threads = 8 waves. Wave w owns
// p-slice [w*192,(w+1)*192). Scores in registers; sparsemax via cross-wave
// reductions (parity-buffered LDS); PV weights stream through per-wave LDS.
// LDS ~33 KB. __launch_bounds__(512,4): cap 128 regs — the kernel needs
// ~90-100 (48 score f32 + 16 AGPR acc + frags); (512,8) forced a spill
// (round 6: VGPR 32, FETCH 1 GB/dispatch scratch traffic). XCD-swizzled grid.
#define WSTR 40  // ushort stride of wbuf rows

__global__ __launch_bounds__(512, 4) void k_attn_mfma(
    const unsigned short* __restrict__ shi, const unsigned short* __restrict__ slo,
    const unsigned short* __restrict__ khi, const unsigned short* __restrict__ klo,
    const unsigned short* __restrict__ vthi, const unsigned short* __restrict__ vtlo,
    const float* __restrict__ log_temp,
    unsigned short* __restrict__ swhi, unsigned short* __restrict__ swlo,
    unsigned short* __restrict__ ohi, unsigned short* __restrict__ olo) {
  __shared__ float part[8][2][2][20];             // 5120 B reduction scratch
  __shared__ unsigned short wbufh[8][16 * WSTR];  // 10240 B per-wave weights hi
  __shared__ unsigned short wbufl[8][16 * WSTR];  // 10240 B per-wave weights lo
  __shared__ float red2[8][16][20];               // 10240 B dt-chunked reduce
  const int t = threadIdx.x;
  const int w = t >> 6, lane = t & 63;
  const int l16 = lane & 15, l4 = lane >> 4;
  // XCD-aware swizzle: grid 2048 = 8 XCDs x 256; keep each (b,h)'s 64
  // tiles on one XCD so its L2 holds that K/V panel (T1, bijective).
  const int bid = blockIdx.x;
  const int tile = (bid & 7) * 256 + (bid >> 3);
  const int stile = tile & 63;
  const int bh = tile >> 6;
  const int h = bh & 15;
  const int s0 = stile * 16;

  float lt = log_temp[h];
  lt = fminf(fmaxf(lt, -4.f), 4.f);
  const float inv_scale = 1.f / (8.f * expf(lt));

  const size_t arow = ((size_t)bh * S + s0 + l16) * HD + 8 * l4;
  short8v ahi0 = *(const short8v*)(shi + arow);
  short8v ahi1 = *(const short8v*)(shi + arow + 32);
  short8v alo0 = *(const short8v*)(slo + arow);
  short8v alo1 = *(const short8v*)(slo + arow + 32);

  float z0[6][4], z1[6][4];
  const size_t kb = (size_t)bh * PT * HD;
#pragma unroll
  for (int pp = 0; pp < 6; ++pp) {
    const int pt0 = w * 12 + pp * 2;
    const size_t k0 = kb + ((size_t)(pt0 * 16 + l16)) * HD + 8 * l4;
    const size_t k1 = k0 + 16 * HD;
    f32x4 a0 = {0.f, 0.f, 0.f, 0.f}, a1 = {0.f, 0.f, 0.f, 0.f};
    {
      short8v b00 = *(const short8v*)(khi + k0);
      short8v b01 = *(const short8v*)(khi + k0 + 32);
      short8v b10 = *(const short8v*)(khi + k1);
      short8v b11 = *(const short8v*)(khi + k1 + 32);
      a0 = __builtin_amdgcn_mfma_f32_16x16x32_bf16(ahi0, b00, a0, 0, 0, 0);
      a1 = __builtin_amdgcn_mfma_f32_16x16x32_bf16(ahi0, b10, a1, 0, 0, 0);
      a0 = __builtin_amdgcn_mfma_f32_16x16x32_bf16(ahi1, b01, a0, 0, 0, 0);
      a1 = __builtin_amdgcn_mfma_f32_16x16x32_bf16(ahi1, b11, a1, 0, 0, 0);
      a0 = __builtin_amdgcn_mfma_f32_16x16x32_bf16(alo0, b00, a0, 0, 0, 0);
      a1 = __builtin_amdgcn_mfma_f32_16x16x32_bf16(alo0, b10, a1, 0, 0, 0);
      a0 = __builtin_amdgcn_mfma_f32_16x16x32_bf16(alo1, b01, a0, 0, 0, 0);
      a1 = __builtin_amdgcn_mfma_f32_16x16x32_bf16(alo1, b11, a1, 0, 0, 0);
    }
    {
      short8v c00 = *(const short8v*)(klo + k0);
      short8v c01 = *(const short8v*)(klo + k0 + 32);
      short8v c10 = *(const short8v*)(klo + k1);
      short8v c11 = *(const short8v*)(klo + k1 + 32);
      a0 = __builtin_amdgcn_mfma_f32_16x16x32_bf16(ahi0, c00, a0, 0, 0, 0);
      a1 = __builtin_amdgcn_mfma_f32_16x16x32_bf16(ahi0, c10, a1, 0, 0, 0);
      a0 = __builtin_amdgcn_mfma_f32_16x16x32_bf16(ahi1, c01, a0, 0, 0, 0);
      a1 = __builtin_amdgcn_mfma_f32_16x16x32_bf16(ahi1, c11, a1, 0, 0, 0);
    }
#pragma unroll
    for (int i = 0; i < 4; ++i) {
      const int sg = s0 + l4 * 4 + i;
      const int p0i = pt0 * 16 + l16;
      z0[pp][i] = (p0i > P0 + sg) ? -1e9f : a0[i] * inv_scale;
      z1[pp][i] = (p0i + 16 > P0 + sg) ? -1e9f : a1[i] * inv_scale;
    }
  }

  // ---- row max ----
  float mx[4];
#pragma unroll
  for (int i = 0; i < 4; ++i) {
    float m = -1e30f;
#pragma unroll
    for (int pp = 0; pp < 6; ++pp) m = fmaxf(m, fmaxf(z0[pp][i], z1[pp][i]));
    mx[i] = m;
  }
#pragma unroll
  for (int off = 1; off <= 8; off <<= 1)
#pragma unroll
    for (int i = 0; i < 4; ++i) mx[i] = fmaxf(mx[i], __shfl_xor(mx[i], off, 64));
  if (l16 == 0) {
#pragma unroll
    for (int i = 0; i < 4; ++i) part[w][0][0][l4 * 4 + i] = mx[i];
  }
  __syncthreads();
  float tlo[4], thi[4];
  {
    float m4[4] = {-1e30f, -1e30f, -1e30f, -1e30f};
#pragma unroll
    for (int ww = 0; ww < 8; ++ww) {
      f32x4 pv = *(const f32x4*)&part[ww][0][0][l4 * 4];
#pragma unroll
      for (int i = 0; i < 4; ++i) m4[i] = fmaxf(m4[i], pv[i]);
    }
#pragma unroll
    for (int i = 0; i < 4; ++i) { thi[i] = m4[i]; tlo[i] = m4[i] - 1.f; }
  }

  // ---- bisection ----
  for (int it = 0; it < 10; ++it) {
    const int sl = (it + 1) & 1;
    float s4[4];
#pragma unroll
    for (int i = 0; i < 4; ++i) {
      const float mid = 0.5f * (tlo[i] + thi[i]);
      float s = 0.f;
#pragma unroll
      for (int pp = 0; pp < 6; ++pp)
        s += fmaxf(z0[pp][i] - mid, 0.f) + fmaxf(z1[pp][i] - mid, 0.f);
      s4[i] = s;
    }
#pragma unroll
    for (int off = 1; off <= 8; off <<= 1)
#pragma unroll
      for (int i = 0; i < 4; ++i) s4[i] += __shfl_xor(s4[i], off, 64);
    if (l16 == 0) {
#pragma unroll
      for (int i = 0; i < 4; ++i) part[w][sl][0][l4 * 4 + i] = s4[i];
    }
    __syncthreads();
    float rs[4] = {0.f, 0.f, 0.f, 0.f};
#pragma unroll
    for (int ww = 0; ww < 8; ++ww) {
      f32x4 pv = *(const f32x4*)&part[ww][sl][0][l4 * 4];
#pragma unroll
      for (int i = 0; i < 4; ++i) rs[i] += pv[i];
    }
#pragma unroll
    for (int i = 0; i < 4; ++i) {
      const float mid = 0.5f * (tlo[i] + thi[i]);
      if (rs[i] >= 1.f) tlo[i] = mid; else thi[i] = mid;
    }
  }

  // ---- Michelot exact finalize ----
  float tau[4];
#pragma unroll
  for (int i = 0; i < 4; ++i) tau[i] = tlo[i];
  for (int it = 0; it < 4; ++it) {
    const int sl = (11 + it) & 1;
    float c4[4], s4[4];
#pragma unroll
    for (int i = 0; i < 4; ++i) {
      float c = 0.f, s = 0.f;
#pragma unroll
      for (int pp = 0; pp < 6; ++pp) {
        float a = z0[pp][i];
        if (a > tau[i]) { c += 1.f; s += a; }
        float b = z1[pp][i];
        if (b > tau[i]) { c += 1.f; s += b; }
      }
      c4[i] = c; s4[i] = s;
    }
#pragma unroll
    for (int off = 1; off <= 8; off <<= 1)
#pragma unroll
      for (int i = 0; i < 4; ++i) {
        c4[i] += __shfl_xor(c4[i], off, 64);
        s4[i] += __shfl_xor(s4[i], off, 64);
      }
    if (l16 == 0) {
#pragma unroll
      for (int i = 0; i < 4; ++i) {
        part[w][sl][0][l4 * 4 + i] = c4[i];
        part[w][sl][1][l4 * 4 + i] = s4[i];
      }
    }
    __syncthreads();
    float rc[4] = {0.f, 0.f, 0.f, 0.f}, rs[4] = {0.f, 0.f, 0.f, 0.f};
#pragma unroll
    for (int ww = 0; ww < 8; ++ww) {
      f32x4 pc = *(const f32x4*)&part[ww][sl][0][l4 * 4];
      f32x4 ps = *(const f32x4*)&part[ww][sl][1][l4 * 4];
#pragma unroll
      for (int i = 0; i < 4; ++i) { rc[i] += pc[i]; rs[i] += ps[i]; }
    }
#pragma unroll
    for (int i = 0; i < 4; ++i) tau[i] = (rs[i] - 1.f) / rc[i];
  }

  // ---- PV ----
  f32x4 acc[4];
#pragma unroll
  for (int dt = 0; dt < 4; ++dt) acc[dt] = (f32x4){0.f, 0.f, 0.f, 0.f};
  const size_t vb = (size_t)bh * HD * PT;
  unsigned short* wh = wbufh[w];
  unsigned short* wl = wbufl[w];
#pragma unroll
  for (int kk = 0; kk < 6; ++kk) {
    const int ks = w * 6 + kk;
#pragma unroll
    for (int i = 0; i < 4; ++i) {
      const int row = l4 * 4 + i;
      float w0 = fmaxf(z0[kk][i] - tau[i], 0.f);
      float w1 = fmaxf(z1[kk][i] - tau[i], 0.f);
      unsigned short h0 = bf16_rne(w0);
      unsigned short h1 = bf16_rne(w1);
      wh[row * WSTR + l16] = h0;
      wl[row * WSTR + l16] = bf16_rne(w0 - bf16_f(h0));
      wh[row * WSTR + 16 + l16] = h1;
      wl[row * WSTR + 16 + l16] = bf16_rne(w1 - bf16_f(h1));
    }
    asm volatile("s_waitcnt lgkmcnt(0)" ::: "memory");  // wave-local W->R
    __builtin_amdgcn_sched_barrier(0);
    short8v wah = *(const short8v*)(wh + l16 * WSTR + 8 * l4);
    short8v wal = *(const short8v*)(wl + l16 * WSTR + 8 * l4);
#pragma unroll
    for (int dt = 0; dt < 4; ++dt) {
      const size_t vo = vb + (size_t)(dt * 16 + l16) * PT + ks * 32 + 8 * l4;
      short8v vh = *(const short8v*)(vthi + vo);
      short8v vl = *(const short8v*)(vtlo + vo);
      acc[dt] = __builtin_amdgcn_mfma_f32_16x16x32_bf16(wah, vh, acc[dt], 0, 0, 0);
      acc[dt] = __builtin_amdgcn_mfma_f32_16x16x32_bf16(wah, vl, acc[dt], 0, 0, 0);
      acc[dt] = __builtin_amdgcn_mfma_f32_16x16x32_bf16(wal, vh, acc[dt], 0, 0, 0);
    }
  }

  // ---- cross-wave reduce, dt-chunked (LDS-lean) + writes ----
  for (int dt = 0; dt < 4; ++dt) {
    __syncthreads();   // red2 free (prev chunk consumed / wbuf reads done)
#pragma unroll
    for (int i = 0; i < 4; ++i)
      red2[w][l4 * 4 + i][l16] = acc[dt][i];
    __syncthreads();
    if (t < 256) {
      const int row = t >> 4, d16 = t & 15;
      float sum = 0.f;
#pragma unroll
      for (int ww = 0; ww < 8; ++ww) sum += red2[ww][row][d16];
      const int d = dt * 16 + d16;
      const int sg = s0 + row;
      unsigned short hb = bf16_rne(sum);
      unsigned short lb = bf16_rne(sum - bf16_f(hb));
      const size_t rw = ((size_t)((bh >> 4) * S + sg)) * DIM + h * HD + d;
      swhi[rw] = hb;
      swlo[rw] = lb;
      const size_t oi = ((size_t)bh * S + sg) * HD + d;
      ohi[oi] = hb;
      olo[oi] = lb;
    }
  }
}

// ----------------------------------------------------------- layernorm ----
__global__ __launch_bounds__(256) void k_layernorm(float* __restrict__ out,
                                                   const float* __restrict__ gamma,
                                                   const float* __restrict__ beta) {
  const int W = 2 * DIM;
  const int r = blockIdx.x;
  float* row = out + (size_t)r * W;
  const int t = threadIdx.x;
  float4 vals[2];
  float sum = 0.f, sq = 0.f;
#pragma unroll
  for (int i = 0; i < 2; ++i) {
    float4 v = *(const float4*)(row + (i * 256 + t) * 4);
    vals[i] = v;
    sum += v.x + v.y + v.z + v.w;
    sq += v.x * v.x + v.y * v.y + v.z * v.z + v.w * v.w;
  }
#pragma unroll
  for (int off = 32; off >= 1; off >>= 1) {
    sum += __shfl_xor(sum, off, 64);
    sq  += __shfl_xor(sq,  off, 64);
  }
  __shared__ float rs[4], rq[4];
  const int wave = t >> 6, lane = t & 63;
  if (lane == 0) { rs[wave] = sum; rq[wave] = sq; }
  __syncthreads();
  sum = rs[0] + rs[1] + rs[2] + rs[3];
  sq  = rq[0] + rq[1] + rq[2] + rq[3];
  const float mean = sum / W;
  const float var = sq / W - mean * mean;
  const float rstd = rsqrtf(var + 1e-5f);
#pragma unroll
  for (int i = 0; i < 2; ++i) {
    int base = (i * 256 + t) * 4;
    float4 v = vals[i];
    float4 g = *(const float4*)(gamma + base);
    float4 bb = *(const float4*)(beta + base);
    v.x = (v.x - mean) * rstd * g.x + bb.x;
    v.y = (v.y - mean) * rstd * g.y + bb.y;
    v.z = (v.z - mean) * rstd * g.z + bb.z;
    v.w = (v.w - mean) * rstd * g.w + bb.w;
    *(float4*)(row + base) = v;
  }
}

// ---------------------------------------------------------------- launch --
extern "C" void kernel_launch(void* const* d_in, const int* in_sizes, int n_in,
                              void* d_out, int out_size, void* d_ws, size_t ws_size,
                              hipStream_t stream) {
  const float* zr       = (const float*)d_in[0];
  const float* zi       = (const float*)d_in[1];
  const float* stored   = (const float*)d_in[3];
  const float* Wq       = (const float*)d_in[4];
  const float* Wk       = (const float*)d_in[5];
  const float* Wv       = (const float*)d_in[6];
  const float* Wo       = (const float*)d_in[7];
  const float* bo       = (const float*)d_in[8];
  const float* log_temp = (const float*)d_in[9];
  const float* gamma    = (const float*)d_in[10];
  const float* beta     = (const float*)d_in[11];
  float* out = (float*)d_out;

  // --- workspace layout, 64 MB peak with lifetime overlays ---
  char* base = (char*)d_ws;
  float* patt = (float*)(base + (size_t)0);                       // 0-12 MB
  unsigned short* vthi = (unsigned short*)(base + (size_t)0);     // 0-6  (over dead patt)
  unsigned short* vtlo = (unsigned short*)(base + (6u << 20));    // 6-12
  unsigned short* phi  = (unsigned short*)(base + (12u << 20));   // 12-18
  unsigned short* plo  = (unsigned short*)(base + (18u << 20));   // 18-24
  unsigned short* swhi = (unsigned short*)(base + (12u << 20));   // 12-16 (over dead phi/plo)
  unsigned short* swlo = (unsigned short*)(base + (16u << 20));   // 16-20
  unsigned short* wqh  = (unsigned short*)(base + (24u << 20));   // 24-26
  unsigned short* wql  = (unsigned short*)(base + (26u << 20));   // 26-28
  unsigned short* wkh  = (unsigned short*)(base + (28u << 20));   // 28-30
  unsigned short* wkl  = (unsigned short*)(base + (30u << 20));   // 30-32
  unsigned short* wvh  = (unsigned short*)(base + (32u << 20));   // 32-34
  unsigned short* wvl  = (unsigned short*)(base + (34u << 20));   // 34-36
  unsigned short* woh  = (unsigned short*)(base + (24u << 20));   // 24-28 (over dead wq/wk)
  unsigned short* wol  = (unsigned short*)(base + (28u << 20));   // 28-32
  float* mag = (float*)(base + (36u << 20));                      // 36-44
  unsigned short* qhi = (unsigned short*)(base + (36u << 20));    // 36-40 (over dead mag)
  unsigned short* qlo = (unsigned short*)(base + (40u << 20));    // 40-44
  unsigned short* s1hi = (unsigned short*)(base + (44u << 20));   // 44-48
  unsigned short* s1lo = (unsigned short*)(base + (48u << 20));   // 48-52
  unsigned short* khi  = (unsigned short*)(base + (52u << 20));   // 52-58
  unsigned short* klo  = (unsigned short*)(base + (58u << 20));   // 58-64

  const int n4 = B * S * DIM / 4;            // 524288
  k_mag<<<(n4 + 255) / 256, 256, 0, stream>>>(zr, zi, mag, n4);
  const int p4 = B * PT * DIM / 4;           // 786432
  k_patt<<<(p4 + 255) / 256, 256, 0, stream>>>(stored, mag, patt, p4);

  // splits: patterns + projection weights
  k_split_plain<<<p4 / 256, 256, 0, stream>>>(patt, phi, plo, p4);
  const int w4 = DIM * DIM / 4;              // 262144
  k_split_plain<<<w4 / 256, 256, 0, stream>>>(Wq, wqh, wql, w4);
  k_split_plain<<<w4 / 256, 256, 0, stream>>>(Wk, wkh, wkl, w4);
  k_split_plain<<<w4 / 256, 256, 0, stream>>>(Wv, wvh, wvl, w4);

  // Q = mag @ Wq^T  (A rows remapped into patt), head-major hi/lo out
  dim3 gq(1024 / 128, 2048 / 128);
  k_gemm_mfma<<<gq, 256, 0, stream>>>(phi, plo, wqh, wql, nullptr, nullptr,
                                      qhi, qlo, 2048, 1024, 1024, 1, 1024, 1);
  // K = patt @ Wk^T, head-major hi/lo out
  dim3 gkv(1024 / 128, 3072 / 128);
  k_gemm_mfma<<<gkv, 256, 0, stream>>>(phi, plo, wkh, wkl, nullptr, nullptr,
                                       khi, klo, 3072, 1024, 1024, 1, 1536, 0);
  // V = patt @ Wv^T, V^T hi/lo out
  k_gemm_mfma<<<gkv, 256, 0, stream>>>(phi, plo, wvh, wvl, nullptr, nullptr,
                                       vthi, vtlo, 3072, 1024, 1024, 2, 1536, 0);

  // Wo split (after wq/wk dead)
  const int wo4 = 2 * DIM * DIM / 4;         // 524288
  k_split_plain<<<wo4 / 256, 256, 0, stream>>>(Wo, woh, wol, wo4);

  const int ablocks = B * H * (S / 16);      // 2048
  k_attn_mfma<<<ablocks, 512, 0, stream>>>(qhi, qlo, khi, klo, vthi, vtlo,
                                           log_temp, swhi, swlo, s1hi, s1lo);
  k_attn_mfma<<<ablocks, 512, 0, stream>>>(s1hi, s1lo, khi, klo, vthi, vtlo,
                                           log_temp, swhi, swlo, qhi, qlo);
  k_attn_mfma<<<ablocks, 512, 0, stream>>>(qhi, qlo, khi, klo, vthi, vtlo,
                                           log_temp, swhi, swlo, s1hi, s1lo);

  // out = sw @ Wo^T + bo, fp32
  dim3 go(2048 / 128, 2048 / 128);
  k_gemm_mfma<<<go, 256, 0, stream>>>(swhi, swlo, woh, wol, bo, out,
                                      nullptr, nullptr, 2048, 2048, 1024, 0, 0, 0);
  k_layernorm<<<B * S, 256, 0, stream>>>(out, gamma, beta);
}